// Round 12
// baseline (366.186 us; speedup 1.0000x reference)
//
#include <hip/hip_runtime.h>

#define N_NODES 100000
#define N_EDGES 600000
#define K_DIM   128
#define NPART   ((N_NODES + 255) / 256)   // 391 scan blocks
#define EBLK    ((N_EDGES + 255) / 256)   // 2344 edge blocks
#define CASTB   (N_NODES * K_DIM / 8 / 256)  // 6250 cast blocks
#define GBLK    ((N_NODES + 127) / 128)   // 782 sage blocks (128 rows)
#define NBLK    ((N_NODES + 63) / 64)     // 1563 ngnn0 blocks (64 rows)
#define VROWS   (GBLK * 128)              // 100096 virtual rows (scratch plane)

typedef unsigned short ushort_t;
typedef short v8s __attribute__((ext_vector_type(8)));   // 8 bf16 = 4 VGPRs
typedef float v4f __attribute__((ext_vector_type(4)));   // MFMA acc frag

// fp32 -> bf16 round-to-nearest-even (inputs are finite; no NaN handling)
__device__ __forceinline__ ushort_t f2b(float f) {
  unsigned u = __builtin_bit_cast(unsigned, f);
  unsigned r = u + 0x7FFFu + ((u >> 16) & 1u);
  return (ushort_t)(r >> 16);
}
__device__ __forceinline__ float b2f(ushort_t h) {
  return __builtin_bit_cast(float, (unsigned)h << 16);
}
// unpack a uint holding two bf16 (little-endian: element0 = low half)
__device__ __forceinline__ float blo(unsigned u) {
  return __builtin_bit_cast(float, u << 16);
}
__device__ __forceinline__ float bhi(unsigned u) {
  return __builtin_bit_cast(float, u & 0xFFFF0000u);
}
__device__ __forceinline__ unsigned pk2(float lo, float hi) {
  return (unsigned)f2b(lo) | ((unsigned)f2b(hi) << 16);
}

// ------------------------------------------------- CSR build + fused prep

__global__ void deg_cast_kernel(const int* __restrict__ dst, int* __restrict__ deg,
                                const float* __restrict__ X, ushort_t* __restrict__ Xb) {
  if (blockIdx.x < EBLK) {
    int e = blockIdx.x * 256 + threadIdx.x;
    if (e < N_EDGES) atomicAdd(&deg[dst[e]], 1);
  } else {
    int i = ((blockIdx.x - EBLK) * 256 + threadIdx.x) * 8;
    if (i >= N_NODES * K_DIM) return;
    float4 v0 = *(const float4*)(X + i);
    float4 v1 = *(const float4*)(X + i + 4);
    ushort4 h0, h1;
    h0.x = f2b(v0.x); h0.y = f2b(v0.y); h0.z = f2b(v0.z); h0.w = f2b(v0.w);
    h1.x = f2b(v1.x); h1.y = f2b(v1.y); h1.z = f2b(v1.z); h1.w = f2b(v1.w);
    *(ushort4*)(Xb + i)     = h0;
    *(ushort4*)(Xb + i + 4) = h1;
  }
}

// scan1 (first NPART blocks) + weight swizzle (next 512 blocks).
// Swizzle layout: sw[(k>>3)*DOUT*8 + n*8 + (k&7)] -> lane's 8 k-values packed.
__global__ void scan1_swz_kernel(
    const int* __restrict__ deg, int* __restrict__ excl, int* __restrict__ partials,
    const float* __restrict__ w0, const float* __restrict__ w1,
    const float* __restrict__ w2, const float* __restrict__ w3,
    const float* __restrict__ w4, const float* __restrict__ w5,
    const float* __restrict__ w6, const float* __restrict__ w7,
    ushort_t* __restrict__ s0, ushort_t* __restrict__ s1,
    ushort_t* __restrict__ s2, ushort_t* __restrict__ s3,
    ushort_t* __restrict__ s4, ushort_t* __restrict__ s5,
    ushort_t* __restrict__ s6, ushort_t* __restrict__ s7) {
  __shared__ int s[256];
  if (blockIdx.x < NPART) {
    int t = threadIdx.x, i = blockIdx.x * 256 + t;
    int v = (i < N_NODES) ? deg[i] : 0;
    s[t] = v;
    __syncthreads();
    for (int off = 1; off < 256; off <<= 1) {
      int x = (t >= off) ? s[t - off] : 0;
      __syncthreads();
      s[t] += x;
      __syncthreads();
    }
    if (i < N_NODES) excl[i] = s[t] - v;
    if (t == 255) partials[blockIdx.x] = s[t];
  } else {
    const int blk = blockIdx.x - NPART;
    const int z = blk >> 6;             // weight id
    const float* W;
    ushort_t* S;
    int dout = 128;
    switch (z) {
      case 0: W = w0; S = s0; break;
      case 1: W = w1; S = s1; break;
      case 2: W = w2; S = s2; break;
      case 3: W = w3; S = s3; break;
      case 4: W = w4; S = s4; break;
      case 5: W = w5; S = s5; break;
      case 6: W = w6; S = s6; dout = 64; break;
      default: W = w7; S = s7; dout = 64; break;
    }
    int t = (blk & 63) * 256 + threadIdx.x;
    if (t >= K_DIM * dout) return;
    int k = t / dout, n = t % dout;
    S[(k >> 3) * (dout * 8) + n * 8 + (k & 7)] = f2b(W[t]);
  }
}

// scan2 deleted (round-7, kept): each scan3 block tree-reduces its own
// prefix over partials[0..b-1] (<=391 values).
__global__ void scan3_kernel(const int* __restrict__ excl, const int* __restrict__ partials,
                             const int* __restrict__ deg, int* __restrict__ row_ptr,
                             int* __restrict__ cursor, float* __restrict__ inv_deg) {
  __shared__ int red[256];
  const int t = threadIdx.x, b = blockIdx.x;
  int sum = 0;
  for (int j = t; j < b && j < NPART; j += 256) sum += partials[j];
  red[t] = sum;
  __syncthreads();
  #pragma unroll
  for (int off = 128; off > 0; off >>= 1) {
    if (t < off) red[t] += red[t + off];
    __syncthreads();
  }
  const int base = red[0];   // sum partials[0..b-1]

  const int i = b * 256 + t;
  if (i < N_NODES) {
    int rp = excl[i] + base;
    row_ptr[i] = rp;
    cursor[i] = rp;
    inv_deg[i] = 1.0f / (float)(deg[i] > 1 ? deg[i] : 1);
  } else if (i == N_NODES) {
    row_ptr[N_NODES] = N_EDGES;
  }
}

__global__ void fill_kernel(const int* __restrict__ src, const int* __restrict__ dst,
                            int* __restrict__ cursor, int* __restrict__ ssrc) {
  int e = blockIdx.x * blockDim.x + threadIdx.x;
  if (e < N_EDGES) {
    int p = atomicAdd(&cursor[dst[e]], 1);
    ssrc[p] = src[e];
  }
}

// ------------------------------------------------- gather bodies
// OLD 4-group chain (used by sage kernels -- proven round-8 config, VGPR 32
// fits the (512,8) cap of 64; DO NOT swap without re-measuring).
template <int STRIDE>
__device__ __forceinline__ void gather16(
    const ushort_t* __restrict__ H, ushort_t* __restrict__ dstbuf,
    const int* __restrict__ row_ptr, const int* __restrict__ ssrc,
    const float* __restrict__ inv_deg, int row0_g, int drow0, int lm, int q) {
  const int c0 = lm * 8;
  for (int rr = 0; rr < 4; ++rr) {
    const int lr = q * 4 + rr;
    const int gv = row0_g + lr;
    const int vv = gv < N_NODES ? gv : N_NODES - 1;  // clamp (edge lists)
    float a[8];
    #pragma unroll
    for (int i = 0; i < 8; ++i) a[i] = 0.f;
    const int beg = row_ptr[vv], end = row_ptr[vv + 1];
    int e = beg;
    for (; e + 4 <= end; e += 4) {
      const int s0 = ssrc[e];
      const int s1 = ssrc[e + 1];
      const int s2 = ssrc[e + 2];
      const int s3 = ssrc[e + 3];
      const uint4 p0 = *(const uint4*)(H + (size_t)s0 * K_DIM + c0);
      const uint4 p1 = *(const uint4*)(H + (size_t)s1 * K_DIM + c0);
      const uint4 p2 = *(const uint4*)(H + (size_t)s2 * K_DIM + c0);
      const uint4 p3 = *(const uint4*)(H + (size_t)s3 * K_DIM + c0);
      a[0] += (blo(p0.x) + blo(p1.x)) + (blo(p2.x) + blo(p3.x));
      a[1] += (bhi(p0.x) + bhi(p1.x)) + (bhi(p2.x) + bhi(p3.x));
      a[2] += (blo(p0.y) + blo(p1.y)) + (blo(p2.y) + blo(p3.y));
      a[3] += (bhi(p0.y) + bhi(p1.y)) + (bhi(p2.y) + bhi(p3.y));
      a[4] += (blo(p0.z) + blo(p1.z)) + (blo(p2.z) + blo(p3.z));
      a[5] += (bhi(p0.z) + bhi(p1.z)) + (bhi(p2.z) + bhi(p3.z));
      a[6] += (blo(p0.w) + blo(p1.w)) + (blo(p2.w) + blo(p3.w));
      a[7] += (bhi(p0.w) + bhi(p1.w)) + (bhi(p2.w) + bhi(p3.w));
    }
    if (e + 2 <= end) {
      const int s0 = ssrc[e];
      const int s1 = ssrc[e + 1];
      const uint4 p0 = *(const uint4*)(H + (size_t)s0 * K_DIM + c0);
      const uint4 p1 = *(const uint4*)(H + (size_t)s1 * K_DIM + c0);
      a[0] += blo(p0.x) + blo(p1.x);
      a[1] += bhi(p0.x) + bhi(p1.x);
      a[2] += blo(p0.y) + blo(p1.y);
      a[3] += bhi(p0.y) + bhi(p1.y);
      a[4] += blo(p0.z) + blo(p1.z);
      a[5] += bhi(p0.z) + bhi(p1.z);
      a[6] += blo(p0.w) + blo(p1.w);
      a[7] += bhi(p0.w) + bhi(p1.w);
      e += 2;
    }
    if (e < end) {
      const int s0 = ssrc[e];
      const uint4 p0 = *(const uint4*)(H + (size_t)s0 * K_DIM + c0);
      a[0] += blo(p0.x);
      a[1] += bhi(p0.x);
      a[2] += blo(p0.y);
      a[3] += bhi(p0.y);
      a[4] += blo(p0.z);
      a[5] += bhi(p0.z);
      a[6] += blo(p0.w);
      a[7] += bhi(p0.w);
    }
    const float sc = inv_deg[vv];
    uint4 ov;
    ov.x = pk2(a[0] * sc, a[1] * sc);
    ov.y = pk2(a[2] * sc, a[3] * sc);
    ov.z = pk2(a[4] * sc, a[5] * sc);
    ov.w = pk2(a[6] * sc, a[7] * sc);
    *(uint4*)&dstbuf[(size_t)(drow0 + lr) * STRIDE + c0] = ov;
  }
}

// ROUND-20: 8-VOLLEY gather (ngnn0 only). The old 4-group chain is TWO
// chained latencies per group (ssrc -> gather), groups serialized: deg-6 row
// = ~4 latencies. ssrc[beg..end) is CONTIGUOUS, so: load all 8 (clamped)
// indices up-front (independent), issue all 8 gathers in one volley
// (clamped duplicates hit the same line -- harmless), accumulate with a
// per-row-uniform predicate. deg<=8 rows (85% at Poisson(6)) = 2 chained
// latencies, ~2x faster. VGPR ~70 peak -> requires the (256,6) cap.
template <int STRIDE>
__device__ __forceinline__ void gather8v(
    const ushort_t* __restrict__ H, ushort_t* __restrict__ dstbuf,
    const int* __restrict__ row_ptr, const int* __restrict__ ssrc,
    const float* __restrict__ inv_deg, int row0_g, int drow0, int lm, int q) {
  const int c0 = lm * 8;
  for (int rr = 0; rr < 4; ++rr) {
    const int lr = q * 4 + rr;
    const int gv = row0_g + lr;
    const int vv = gv < N_NODES ? gv : N_NODES - 1;  // clamp (edge lists)
    float a[8];
    #pragma unroll
    for (int i = 0; i < 8; ++i) a[i] = 0.f;
    const int beg = row_ptr[vv], end = row_ptr[vv + 1];
    for (int e0 = beg; e0 < end; e0 += 8) {
      int idx[8];
      #pragma unroll
      for (int j = 0; j < 8; ++j) {
        int ee = e0 + j;
        ee = ee < end ? ee : end - 1;   // clamp (end > beg guaranteed here)
        idx[j] = ssrc[ee];
      }
      uint4 p[8];
      #pragma unroll
      for (int j = 0; j < 8; ++j)
        p[j] = *(const uint4*)(H + (size_t)idx[j] * K_DIM + c0);
      const int cnt = (end - e0) < 8 ? (end - e0) : 8;
      #pragma unroll
      for (int j = 0; j < 8; ++j) {
        if (j < cnt) {   // per-row-uniform predicate
          a[0] += blo(p[j].x); a[1] += bhi(p[j].x);
          a[2] += blo(p[j].y); a[3] += bhi(p[j].y);
          a[4] += blo(p[j].z); a[5] += bhi(p[j].z);
          a[6] += blo(p[j].w); a[7] += bhi(p[j].w);
        }
      }
    }
    const float sc = inv_deg[vv];
    uint4 ov;
    ov.x = pk2(a[0] * sc, a[1] * sc);
    ov.y = pk2(a[2] * sc, a[3] * sc);
    ov.z = pk2(a[4] * sc, a[5] * sc);
    ov.w = pk2(a[6] * sc, a[7] * sc);
    *(uint4*)&dstbuf[(size_t)(drow0 + lr) * STRIDE + c0] = ov;
  }
}

// ------------------------------------------------- fused SAGE layer (1,2)
// out = act( H@Wself + agg(H)@Wneigh + b ). EXACT round-8 best config:
// global AGG virtual-row plane + 32KB LDS weight buffer, (512,8), Wneigh
// staged first / phase A right after gather. 59-61us measured, best total.
// DO NOT switch to LDS-agg+global-W here: measured 67us (round 9).

template <int DOUT, bool RELU, bool BF16_OUT>
__global__ __launch_bounds__(512, 8) void sage_layer_kernel(
    const ushort_t* __restrict__ H,
    ushort_t* __restrict__ AGG,     // scratch, VROWS x K_DIM bf16
    const ushort_t* __restrict__ Wself_sw, const ushort_t* __restrict__ Wneigh_sw,
    const float* __restrict__ bias,
    const int* __restrict__ row_ptr, const int* __restrict__ ssrc,
    const float* __restrict__ inv_deg,
    ushort_t* __restrict__ Obf, float* __restrict__ Ofp) {
  constexpr int NT  = DOUT / 16;        // n-tiles per wave (8 or 4)
  constexpr int SWN = K_DIM * DOUT;     // W slice ushorts (32 KB / 16 KB)
  constexpr int NW  = SWN / 4096;       // uint4 loads per thread (4 or 2)
  __shared__ __align__(16) ushort_t buf[16384];   // 32 KB

  const int tid   = threadIdx.x;
  const int wv    = tid >> 6;
  const int lane  = tid & 63;
  const int lm    = lane & 15;
  const int q     = lane >> 4;
  const int lrow0 = wv * 16;
  const int row0  = blockIdx.x * 128 + lrow0;   // virtual row base (wave)

  // stage Wneigh FIRST; T14-prefetch Wself into regs
  #pragma unroll
  for (int j = 0; j < NW; ++j)
    *(uint4*)&buf[tid * 8 + j * 4096] = *(const uint4*)&Wneigh_sw[tid * 8 + j * 4096];
  uint4 wreg[NW];
  #pragma unroll
  for (int j = 0; j < NW; ++j)
    wreg[j] = *(const uint4*)&Wself_sw[tid * 8 + j * 4096];
  __syncthreads();   // buf(Wneigh) ready

  gather16<K_DIM>(H, AGG, row_ptr, ssrc, inv_deg, row0, row0, lm, q);

  v4f acc[NT];
  #pragma unroll
  for (int n = 0; n < NT; ++n) acc[n] = (v4f){0.f, 0.f, 0.f, 0.f};

  // ---- phase A: AGG[own virtual rows] @ Wneigh (AGG lines L2-hot)
  const size_t offA = (size_t)(row0 + lm) * K_DIM;
  for (int ks = 0; ks < K_DIM / 32; ++ks) {
    const int ko = ks * 32 + q * 8;
    const v8s a0 = *(const v8s*)(AGG + offA + ko);
    #pragma unroll
    for (int nt = 0; nt < NT; ++nt) {
      const v8s b = *(const v8s*)&buf[((ks * 4 + q) * DOUT + nt * 16 + lm) * 8];
      acc[nt] = __builtin_amdgcn_mfma_f32_16x16x32_bf16(a0, b, acc[nt], 0, 0, 0);
    }
  }
  __syncthreads();   // all waves done reading Wneigh

  #pragma unroll
  for (int j = 0; j < NW; ++j)
    *(uint4*)&buf[tid * 8 + j * 4096] = wreg[j];
  __syncthreads();   // Wself staged

  // ---- phase B: acc += H[own rows] @ Wself
  int ra = row0 + lm;  ra = ra < N_NODES ? ra : N_NODES - 1;
  const size_t off0 = (size_t)ra * K_DIM;
  for (int ks = 0; ks < K_DIM / 32; ++ks) {
    const int ko = ks * 32 + q * 8;
    const v8s a0 = *(const v8s*)(H + off0 + ko);
    #pragma unroll
    for (int nt = 0; nt < NT; ++nt) {
      const v8s b = *(const v8s*)&buf[((ks * 4 + q) * DOUT + nt * 16 + lm) * 8];
      acc[nt] = __builtin_amdgcn_mfma_f32_16x16x32_bf16(a0, b, acc[nt], 0, 0, 0);
    }
  }
  __syncthreads();   // buf free for epilogue

  // ---- epilogue: stage C into buf (C-layout), then coalesced out
  const int base = blockIdx.x * 128;
  if constexpr (BF16_OUT) {
    #pragma unroll
    for (int nt = 0; nt < NT; ++nt) {
      const int col = nt * 16 + lm;
      const float bv = bias[col];
      #pragma unroll
      for (int r = 0; r < 4; ++r) {
        float v = acc[nt][r] + bv;
        if (RELU) v = v > 0.f ? v : 0.f;
        buf[(lrow0 + q * 4 + r) * DOUT + col] = f2b(v);
      }
    }
    __syncthreads();
    #pragma unroll
    for (int i = tid * 8; i < 128 * DOUT; i += 4096) {
      const int rw = i / DOUT;
      if (base + rw < N_NODES)
        *(uint4*)&Obf[(size_t)(base + rw) * DOUT + (i % DOUT)] = *(const uint4*)&buf[i];
    }
  } else {
    float* fb = (float*)buf;    // 8192 floats = 32 KB (DOUT=64)
    #pragma unroll
    for (int nt = 0; nt < NT; ++nt) {
      const int col = nt * 16 + lm;
      const float bv = bias[col];
      #pragma unroll
      for (int r = 0; r < 4; ++r) {
        float v = acc[nt][r] + bv;
        if (RELU) v = v > 0.f ? v : 0.f;
        fb[(lrow0 + q * 4 + r) * DOUT + col] = v;
      }
    }
    __syncthreads();
    #pragma unroll
    for (int i = tid * 4; i < 128 * DOUT; i += 2048) {
      const int rw = i / DOUT;
      if (base + rw < N_NODES)
        *(float4*)&Ofp[(size_t)(base + rw) * DOUT + (i % DOUT)] = *(const float4*)&fb[i];
    }
  }
}

// ------------------------------------------------- ngnn0: sage0+fc+fc2 fused
// Y = relu( relu( relu(X@Ws0 + agg(X)@Wn0 + b0) @ Wf1 + b1 ) @ Wf2 + b2 )
// 64-row blocks (round-11), zero barriers, weights from L2-hot global.
// ROUND-20: gather8v (8-volley, 2 chained latencies for deg<=8) +
// launch_bounds (256,6) for the VGPR headroom (grid is 6.1 blocks/CU, so
// the 6-block cap is not binding; measured occupancy was 4.5-4.6 blocks).

__global__ __launch_bounds__(256, 6) void ngnn0_kernel(
    const ushort_t* __restrict__ X,
    const ushort_t* __restrict__ Ws0, const ushort_t* __restrict__ Wn0,
    const ushort_t* __restrict__ Wf1, const ushort_t* __restrict__ Wf2,
    const float* __restrict__ b0, const float* __restrict__ bf1,
    const float* __restrict__ bf2,
    const int* __restrict__ row_ptr, const int* __restrict__ ssrc,
    const float* __restrict__ inv_deg,
    ushort_t* __restrict__ O) {
  constexpr int NT = 8;
  constexpr int HP = 136;   // 272B row stride = 17*16B: b128-aligned, 2-way banks
  __shared__ __align__(16) ushort_t aggb[64 * HP];   // 17.4 KB

  const int tid   = threadIdx.x;
  const int wv    = tid >> 6;               // 0..3
  const int lane  = tid & 63;
  const int lm    = lane & 15;
  const int q     = lane >> 4;
  const int lrow0 = wv * 16;
  const int row0  = blockIdx.x * 64 + lrow0;

  // ---- gather: aggb[own 16 rows] = mean of neighbor X rows (wave-local)
  gather8v<HP>(X, aggb, row_ptr, ssrc, inv_deg, row0, lrow0, lm, q);

  v4f acc[NT];
  #pragma unroll
  for (int n = 0; n < NT; ++n) acc[n] = (v4f){0.f, 0.f, 0.f, 0.f};

  // ---- phase A: aggb @ Wn0
  for (int ks = 0; ks < K_DIM / 32; ++ks) {
    const int ko = ks * 32 + q * 8;
    const v8s a0 = *(const v8s*)&aggb[(lrow0 + lm) * HP + ko];
    #pragma unroll
    for (int nt = 0; nt < NT; ++nt) {
      const v8s b = *(const v8s*)&Wn0[((ks * 4 + q) * 128 + nt * 16 + lm) * 8];
      acc[nt] = __builtin_amdgcn_mfma_f32_16x16x32_bf16(a0, b, acc[nt], 0, 0, 0);
    }
  }

  // ---- phase B: acc += X[own rows] @ Ws0
  int ra = row0 + lm;  ra = ra < N_NODES ? ra : N_NODES - 1;
  const size_t off0 = (size_t)ra * K_DIM;
  for (int ks = 0; ks < K_DIM / 32; ++ks) {
    const int ko = ks * 32 + q * 8;
    const v8s a0 = *(const v8s*)(X + off0 + ko);
    #pragma unroll
    for (int nt = 0; nt < NT; ++nt) {
      const v8s b = *(const v8s*)&Ws0[((ks * 4 + q) * 128 + nt * 16 + lm) * 8];
      acc[nt] = __builtin_amdgcn_mfma_f32_16x16x32_bf16(a0, b, acc[nt], 0, 0, 0);
    }
  }

  // ---- h0 = relu(acc + b0) -> aggb own rows (C-layout; after phase-A reads
  // in program order -- per-wave DS FIFO keeps read-before-write)
  #pragma unroll
  for (int nt = 0; nt < NT; ++nt) {
    const int col = nt * 16 + lm;
    const float bv = b0[col];
    #pragma unroll
    for (int r = 0; r < 4; ++r) {
      float v = acc[nt][r] + bv;
      v = v > 0.f ? v : 0.f;
      aggb[(lrow0 + q * 4 + r) * HP + col] = f2b(v);
      acc[nt][r] = 0.f;
    }
  }

  // ---- phase C: aggb(h0) @ Wf1
  for (int ks = 0; ks < K_DIM / 32; ++ks) {
    const int ko = ks * 32 + q * 8;
    const v8s a0 = *(const v8s*)&aggb[(lrow0 + lm) * HP + ko];
    #pragma unroll
    for (int nt = 0; nt < NT; ++nt) {
      const v8s b = *(const v8s*)&Wf1[((ks * 4 + q) * 128 + nt * 16 + lm) * 8];
      acc[nt] = __builtin_amdgcn_mfma_f32_16x16x32_bf16(a0, b, acc[nt], 0, 0, 0);
    }
  }

  // ---- h1 = relu(acc + bf1) -> aggb own rows
  #pragma unroll
  for (int nt = 0; nt < NT; ++nt) {
    const int col = nt * 16 + lm;
    const float bv = bf1[col];
    #pragma unroll
    for (int r = 0; r < 4; ++r) {
      float v = acc[nt][r] + bv;
      v = v > 0.f ? v : 0.f;
      aggb[(lrow0 + q * 4 + r) * HP + col] = f2b(v);
      acc[nt][r] = 0.f;
    }
  }

  // ---- phase D: aggb(h1) @ Wf2
  for (int ks = 0; ks < K_DIM / 32; ++ks) {
    const int ko = ks * 32 + q * 8;
    const v8s a0 = *(const v8s*)&aggb[(lrow0 + lm) * HP + ko];
    #pragma unroll
    for (int nt = 0; nt < NT; ++nt) {
      const v8s b = *(const v8s*)&Wf2[((ks * 4 + q) * 128 + nt * 16 + lm) * 8];
      acc[nt] = __builtin_amdgcn_mfma_f32_16x16x32_bf16(a0, b, acc[nt], 0, 0, 0);
    }
  }

  // ---- out = relu(acc + bf2): stage into aggb, then per-wave coalesced
  // write of the wave's own 16 rows (no barrier -- all same-wave data)
  #pragma unroll
  for (int nt = 0; nt < NT; ++nt) {
    const int col = nt * 16 + lm;
    const float bv = bf2[col];
    #pragma unroll
    for (int r = 0; r < 4; ++r) {
      float v = acc[nt][r] + bv;
      v = v > 0.f ? v : 0.f;
      aggb[(lrow0 + q * 4 + r) * HP + col] = f2b(v);
    }
  }
  #pragma unroll
  for (int j = 0; j < 4; ++j) {
    const int idx = j * 64 + lane;    // 0..255: 16 rows x 16 segments
    const int rw  = idx >> 4;
    const int sg  = idx & 15;
    const int grow = row0 + rw;
    if (grow < N_NODES)
      *(uint4*)&O[(size_t)grow * 128 + sg * 8] =
          *(const uint4*)&aggb[(lrow0 + rw) * HP + sg * 8];
  }
}

// ---------------------------------------------------------------- launcher

extern "C" void kernel_launch(void* const* d_in, const int* in_sizes, int n_in,
                              void* d_out, int out_size, void* d_ws, size_t ws_size,
                              hipStream_t stream) {
  const float* x        = (const float*)d_in[0];
  const int*   src      = (const int*)d_in[1];
  const int*   dst      = (const int*)d_in[2];
  const float* w_self0  = (const float*)d_in[3];
  const float* b_self0  = (const float*)d_in[4];
  const float* w_neigh0 = (const float*)d_in[5];
  const float* fc_w     = (const float*)d_in[6];
  const float* fc_b     = (const float*)d_in[7];
  const float* fc2_w    = (const float*)d_in[8];
  const float* fc2_b    = (const float*)d_in[9];
  const float* w_self1  = (const float*)d_in[10];
  const float* b_self1  = (const float*)d_in[11];
  const float* w_neigh1 = (const float*)d_in[12];
  const float* w_self2  = (const float*)d_in[13];
  const float* b_self2  = (const float*)d_in[14];
  const float* w_neigh2 = (const float*)d_in[15];

  char* p = (char*)d_ws;
  auto carve = [&](size_t bytes) {
    void* q = (void*)p;
    p += (bytes + 511) & ~(size_t)511;
    return q;
  };
  const size_t VPLANE = (size_t)VROWS * K_DIM * sizeof(ushort_t);   // 25.6 MB
  ushort_t* X    = (ushort_t*)carve(VPLANE);
  ushort_t* Y    = (ushort_t*)carve(VPLANE);
  ushort_t* Z    = (ushort_t*)carve(VPLANE);
  ushort_t* AGGs = (ushort_t*)carve(VPLANE);
  ushort_t* ws0 = (ushort_t*)carve(K_DIM * 128 * 2);
  ushort_t* wn0 = (ushort_t*)carve(K_DIM * 128 * 2);
  ushort_t* wfc = (ushort_t*)carve(K_DIM * 128 * 2);
  ushort_t* wf2 = (ushort_t*)carve(K_DIM * 128 * 2);
  ushort_t* ws1 = (ushort_t*)carve(K_DIM * 128 * 2);
  ushort_t* wn1 = (ushort_t*)carve(K_DIM * 128 * 2);
  ushort_t* ws2 = (ushort_t*)carve(K_DIM * 64 * 2);
  ushort_t* wn2 = (ushort_t*)carve(K_DIM * 64 * 2);
  int*   ssrc    = (int*)carve((size_t)N_EDGES * 4);
  int*   row_ptr = (int*)carve((size_t)(N_NODES + 1) * 4);
  int*   cursor  = (int*)carve((size_t)N_NODES * 4);
  int*   deg     = (int*)carve((size_t)N_NODES * 4);
  int*   excl    = (int*)carve((size_t)N_NODES * 4);
  int*   parts   = (int*)carve(512 * 4);
  float* inv_deg = (float*)carve((size_t)N_NODES * 4);

  // ---- CSR build (by dst), with cast/swizzle fused into its idle slots
  hipMemsetAsync(deg, 0, (size_t)N_NODES * 4, stream);
  deg_cast_kernel<<<EBLK + CASTB, 256, 0, stream>>>(dst, deg, x, X);
  scan1_swz_kernel<<<NPART + 512, 256, 0, stream>>>(
      deg, excl, parts,
      w_self0, w_neigh0, fc_w, fc2_w, w_self1, w_neigh1, w_self2, w_neigh2,
      ws0, wn0, wfc, wf2, ws1, wn1, ws2, wn2);
  scan3_kernel<<<((N_NODES + 1) + 255) / 256, 256, 0, stream>>>(excl, parts, deg,
                                                                row_ptr, cursor, inv_deg);
  fill_kernel<<<EBLK, 256, 0, stream>>>(src, dst, cursor, ssrc);

  // ---- network: 3 dispatches.
  // ngnn0 (sage0+fc+fc2): X -> Y  (64-row blocks, 8-volley gather)
  ngnn0_kernel<<<NBLK, 256, 0, stream>>>(
      X, ws0, wn0, wfc, wf2, b_self0, fc_b, fc2_b,
      row_ptr, ssrc, inv_deg, Y);
  // layer 1: relu(Y@Ws1 + agg(Y)@Wn1 + b) -> Z
  sage_layer_kernel<128, true, true><<<GBLK, 512, 0, stream>>>(
      Y, AGGs, ws1, wn1, b_self1, row_ptr, ssrc, inv_deg, Z, nullptr);
  // layer 2: Z@Ws2 + agg(Z)@Wn2 + b -> d_out (fp32, DOUT=64)
  sage_layer_kernel<64, false, false><<<GBLK, 512, 0, stream>>>(
      Z, AGGs, ws2, wn2, b_self2, row_ptr, ssrc, inv_deg, nullptr, (float*)d_out);
}

// Round 13
// 345.404 us; speedup vs baseline: 1.0602x; 1.0602x over previous
//
#include <hip/hip_runtime.h>

#define N_NODES 100000
#define N_EDGES 600000
#define K_DIM   128
#define NPART   ((N_NODES + 255) / 256)   // 391 scan blocks
#define EBLK    ((N_EDGES + 255) / 256)   // 2344 edge blocks
#define CASTB   (N_NODES * K_DIM / 8 / 256)  // 6250 cast blocks
#define GBLK    ((N_NODES + 127) / 128)   // 782 sage blocks (128 rows)
#define NBLK    ((N_NODES + 31) / 32)     // 3125 ngnn0 blocks (32 rows)
#define VROWS   (GBLK * 128)              // 100096 virtual rows (scratch plane)

typedef unsigned short ushort_t;
typedef short v8s __attribute__((ext_vector_type(8)));   // 8 bf16 = 4 VGPRs
typedef float v4f __attribute__((ext_vector_type(4)));   // MFMA acc frag

// fp32 -> bf16 round-to-nearest-even (inputs are finite; no NaN handling)
__device__ __forceinline__ ushort_t f2b(float f) {
  unsigned u = __builtin_bit_cast(unsigned, f);
  unsigned r = u + 0x7FFFu + ((u >> 16) & 1u);
  return (ushort_t)(r >> 16);
}
__device__ __forceinline__ float b2f(ushort_t h) {
  return __builtin_bit_cast(float, (unsigned)h << 16);
}
// unpack a uint holding two bf16 (little-endian: element0 = low half)
__device__ __forceinline__ float blo(unsigned u) {
  return __builtin_bit_cast(float, u << 16);
}
__device__ __forceinline__ float bhi(unsigned u) {
  return __builtin_bit_cast(float, u & 0xFFFF0000u);
}
__device__ __forceinline__ unsigned pk2(float lo, float hi) {
  return (unsigned)f2b(lo) | ((unsigned)f2b(hi) << 16);
}

// ------------------------------------------------- CSR build + fused prep

__global__ void deg_cast_kernel(const int* __restrict__ dst, int* __restrict__ deg,
                                const float* __restrict__ X, ushort_t* __restrict__ Xb) {
  if (blockIdx.x < EBLK) {
    int e = blockIdx.x * 256 + threadIdx.x;
    if (e < N_EDGES) atomicAdd(&deg[dst[e]], 1);
  } else {
    int i = ((blockIdx.x - EBLK) * 256 + threadIdx.x) * 8;
    if (i >= N_NODES * K_DIM) return;
    float4 v0 = *(const float4*)(X + i);
    float4 v1 = *(const float4*)(X + i + 4);
    ushort4 h0, h1;
    h0.x = f2b(v0.x); h0.y = f2b(v0.y); h0.z = f2b(v0.z); h0.w = f2b(v0.w);
    h1.x = f2b(v1.x); h1.y = f2b(v1.y); h1.z = f2b(v1.z); h1.w = f2b(v1.w);
    *(ushort4*)(Xb + i)     = h0;
    *(ushort4*)(Xb + i + 4) = h1;
  }
}

// scan1 (first NPART blocks) + weight swizzle (next 512 blocks).
// Swizzle layout: sw[(k>>3)*DOUT*8 + n*8 + (k&7)] -> lane's 8 k-values packed.
__global__ void scan1_swz_kernel(
    const int* __restrict__ deg, int* __restrict__ excl, int* __restrict__ partials,
    const float* __restrict__ w0, const float* __restrict__ w1,
    const float* __restrict__ w2, const float* __restrict__ w3,
    const float* __restrict__ w4, const float* __restrict__ w5,
    const float* __restrict__ w6, const float* __restrict__ w7,
    ushort_t* __restrict__ s0, ushort_t* __restrict__ s1,
    ushort_t* __restrict__ s2, ushort_t* __restrict__ s3,
    ushort_t* __restrict__ s4, ushort_t* __restrict__ s5,
    ushort_t* __restrict__ s6, ushort_t* __restrict__ s7) {
  __shared__ int s[256];
  if (blockIdx.x < NPART) {
    int t = threadIdx.x, i = blockIdx.x * 256 + t;
    int v = (i < N_NODES) ? deg[i] : 0;
    s[t] = v;
    __syncthreads();
    for (int off = 1; off < 256; off <<= 1) {
      int x = (t >= off) ? s[t - off] : 0;
      __syncthreads();
      s[t] += x;
      __syncthreads();
    }
    if (i < N_NODES) excl[i] = s[t] - v;
    if (t == 255) partials[blockIdx.x] = s[t];
  } else {
    const int blk = blockIdx.x - NPART;
    const int z = blk >> 6;             // weight id
    const float* W;
    ushort_t* S;
    int dout = 128;
    switch (z) {
      case 0: W = w0; S = s0; break;
      case 1: W = w1; S = s1; break;
      case 2: W = w2; S = s2; break;
      case 3: W = w3; S = s3; break;
      case 4: W = w4; S = s4; break;
      case 5: W = w5; S = s5; break;
      case 6: W = w6; S = s6; dout = 64; break;
      default: W = w7; S = s7; dout = 64; break;
    }
    int t = (blk & 63) * 256 + threadIdx.x;
    if (t >= K_DIM * dout) return;
    int k = t / dout, n = t % dout;
    S[(k >> 3) * (dout * 8) + n * 8 + (k & 7)] = f2b(W[t]);
  }
}

// scan2 deleted (round-7, kept): each scan3 block tree-reduces its own
// prefix over partials[0..b-1] (<=391 values).
__global__ void scan3_kernel(const int* __restrict__ excl, const int* __restrict__ partials,
                             const int* __restrict__ deg, int* __restrict__ row_ptr,
                             int* __restrict__ cursor, float* __restrict__ inv_deg) {
  __shared__ int red[256];
  const int t = threadIdx.x, b = blockIdx.x;
  int sum = 0;
  for (int j = t; j < b && j < NPART; j += 256) sum += partials[j];
  red[t] = sum;
  __syncthreads();
  #pragma unroll
  for (int off = 128; off > 0; off >>= 1) {
    if (t < off) red[t] += red[t + off];
    __syncthreads();
  }
  const int base = red[0];   // sum partials[0..b-1]

  const int i = b * 256 + t;
  if (i < N_NODES) {
    int rp = excl[i] + base;
    row_ptr[i] = rp;
    cursor[i] = rp;
    inv_deg[i] = 1.0f / (float)(deg[i] > 1 ? deg[i] : 1);
  } else if (i == N_NODES) {
    row_ptr[N_NODES] = N_EDGES;
  }
}

__global__ void fill_kernel(const int* __restrict__ src, const int* __restrict__ dst,
                            int* __restrict__ cursor, int* __restrict__ ssrc) {
  int e = blockIdx.x * blockDim.x + threadIdx.x;
  if (e < N_EDGES) {
    int p = atomicAdd(&cursor[dst[e]], 1);
    ssrc[p] = src[e];
  }
}

// ------------------------------------------------- gather body (round-11 proven)
// Wave aggregates its own 16 rows. 16 lanes/row (lane lm covers cols lm*8..+7),
// 4 rows in parallel (q), 4 passes; 4-edge unroll keeps 4 gathers in flight.
// STRIDE selects LDS (HP) vs global (K_DIM) destination.
// ROUND-13 NOTE: do NOT replace with the 8-volley variant -- round-12 A/B:
// volley cut traffic but collapsed occupancy (57->39%) and cost +20us.
template <int STRIDE>
__device__ __forceinline__ void gather16(
    const ushort_t* __restrict__ H, ushort_t* __restrict__ dstbuf,
    const int* __restrict__ row_ptr, const int* __restrict__ ssrc,
    const float* __restrict__ inv_deg, int row0_g, int drow0, int lm, int q) {
  const int c0 = lm * 8;
  for (int rr = 0; rr < 4; ++rr) {
    const int lr = q * 4 + rr;
    const int gv = row0_g + lr;
    const int vv = gv < N_NODES ? gv : N_NODES - 1;  // clamp (edge lists)
    float a[8];
    #pragma unroll
    for (int i = 0; i < 8; ++i) a[i] = 0.f;
    const int beg = row_ptr[vv], end = row_ptr[vv + 1];
    int e = beg;
    for (; e + 4 <= end; e += 4) {
      const int s0 = ssrc[e];
      const int s1 = ssrc[e + 1];
      const int s2 = ssrc[e + 2];
      const int s3 = ssrc[e + 3];
      const uint4 p0 = *(const uint4*)(H + (size_t)s0 * K_DIM + c0);
      const uint4 p1 = *(const uint4*)(H + (size_t)s1 * K_DIM + c0);
      const uint4 p2 = *(const uint4*)(H + (size_t)s2 * K_DIM + c0);
      const uint4 p3 = *(const uint4*)(H + (size_t)s3 * K_DIM + c0);
      a[0] += (blo(p0.x) + blo(p1.x)) + (blo(p2.x) + blo(p3.x));
      a[1] += (bhi(p0.x) + bhi(p1.x)) + (bhi(p2.x) + bhi(p3.x));
      a[2] += (blo(p0.y) + blo(p1.y)) + (blo(p2.y) + blo(p3.y));
      a[3] += (bhi(p0.y) + bhi(p1.y)) + (bhi(p2.y) + bhi(p3.y));
      a[4] += (blo(p0.z) + blo(p1.z)) + (blo(p2.z) + blo(p3.z));
      a[5] += (bhi(p0.z) + bhi(p1.z)) + (bhi(p2.z) + bhi(p3.z));
      a[6] += (blo(p0.w) + blo(p1.w)) + (blo(p2.w) + blo(p3.w));
      a[7] += (bhi(p0.w) + bhi(p1.w)) + (bhi(p2.w) + bhi(p3.w));
    }
    if (e + 2 <= end) {
      const int s0 = ssrc[e];
      const int s1 = ssrc[e + 1];
      const uint4 p0 = *(const uint4*)(H + (size_t)s0 * K_DIM + c0);
      const uint4 p1 = *(const uint4*)(H + (size_t)s1 * K_DIM + c0);
      a[0] += blo(p0.x) + blo(p1.x);
      a[1] += bhi(p0.x) + bhi(p1.x);
      a[2] += blo(p0.y) + blo(p1.y);
      a[3] += bhi(p0.y) + bhi(p1.y);
      a[4] += blo(p0.z) + blo(p1.z);
      a[5] += bhi(p0.z) + bhi(p1.z);
      a[6] += blo(p0.w) + blo(p1.w);
      a[7] += bhi(p0.w) + bhi(p1.w);
      e += 2;
    }
    if (e < end) {
      const int s0 = ssrc[e];
      const uint4 p0 = *(const uint4*)(H + (size_t)s0 * K_DIM + c0);
      a[0] += blo(p0.x);
      a[1] += bhi(p0.x);
      a[2] += blo(p0.y);
      a[3] += bhi(p0.y);
      a[4] += blo(p0.z);
      a[5] += bhi(p0.z);
      a[6] += blo(p0.w);
      a[7] += bhi(p0.w);
    }
    const float sc = inv_deg[vv];
    uint4 ov;
    ov.x = pk2(a[0] * sc, a[1] * sc);
    ov.y = pk2(a[2] * sc, a[3] * sc);
    ov.z = pk2(a[4] * sc, a[5] * sc);
    ov.w = pk2(a[6] * sc, a[7] * sc);
    *(uint4*)&dstbuf[(size_t)(drow0 + lr) * STRIDE + c0] = ov;
  }
}

// ------------------------------------------------- fused SAGE layer (1,2)
// out = act( H@Wself + agg(H)@Wneigh + b ). EXACT round-8 best config:
// global AGG virtual-row plane + 32KB LDS weight buffer, (512,8), Wneigh
// staged first / phase A right after gather. 59-61us measured, best total.
// DO NOT switch to LDS-agg+global-W here: measured 67us (round 9).

template <int DOUT, bool RELU, bool BF16_OUT>
__global__ __launch_bounds__(512, 8) void sage_layer_kernel(
    const ushort_t* __restrict__ H,
    ushort_t* __restrict__ AGG,     // scratch, VROWS x K_DIM bf16
    const ushort_t* __restrict__ Wself_sw, const ushort_t* __restrict__ Wneigh_sw,
    const float* __restrict__ bias,
    const int* __restrict__ row_ptr, const int* __restrict__ ssrc,
    const float* __restrict__ inv_deg,
    ushort_t* __restrict__ Obf, float* __restrict__ Ofp) {
  constexpr int NT  = DOUT / 16;        // n-tiles per wave (8 or 4)
  constexpr int SWN = K_DIM * DOUT;     // W slice ushorts (32 KB / 16 KB)
  constexpr int NW  = SWN / 4096;       // uint4 loads per thread (4 or 2)
  __shared__ __align__(16) ushort_t buf[16384];   // 32 KB

  const int tid   = threadIdx.x;
  const int wv    = tid >> 6;
  const int lane  = tid & 63;
  const int lm    = lane & 15;
  const int q     = lane >> 4;
  const int lrow0 = wv * 16;
  const int row0  = blockIdx.x * 128 + lrow0;   // virtual row base (wave)

  // stage Wneigh FIRST; T14-prefetch Wself into regs
  #pragma unroll
  for (int j = 0; j < NW; ++j)
    *(uint4*)&buf[tid * 8 + j * 4096] = *(const uint4*)&Wneigh_sw[tid * 8 + j * 4096];
  uint4 wreg[NW];
  #pragma unroll
  for (int j = 0; j < NW; ++j)
    wreg[j] = *(const uint4*)&Wself_sw[tid * 8 + j * 4096];
  __syncthreads();   // buf(Wneigh) ready

  gather16<K_DIM>(H, AGG, row_ptr, ssrc, inv_deg, row0, row0, lm, q);

  v4f acc[NT];
  #pragma unroll
  for (int n = 0; n < NT; ++n) acc[n] = (v4f){0.f, 0.f, 0.f, 0.f};

  // ---- phase A: AGG[own virtual rows] @ Wneigh (AGG lines L2-hot)
  const size_t offA = (size_t)(row0 + lm) * K_DIM;
  for (int ks = 0; ks < K_DIM / 32; ++ks) {
    const int ko = ks * 32 + q * 8;
    const v8s a0 = *(const v8s*)(AGG + offA + ko);
    #pragma unroll
    for (int nt = 0; nt < NT; ++nt) {
      const v8s b = *(const v8s*)&buf[((ks * 4 + q) * DOUT + nt * 16 + lm) * 8];
      acc[nt] = __builtin_amdgcn_mfma_f32_16x16x32_bf16(a0, b, acc[nt], 0, 0, 0);
    }
  }
  __syncthreads();   // all waves done reading Wneigh

  #pragma unroll
  for (int j = 0; j < NW; ++j)
    *(uint4*)&buf[tid * 8 + j * 4096] = wreg[j];
  __syncthreads();   // Wself staged

  // ---- phase B: acc += H[own rows] @ Wself
  int ra = row0 + lm;  ra = ra < N_NODES ? ra : N_NODES - 1;
  const size_t off0 = (size_t)ra * K_DIM;
  for (int ks = 0; ks < K_DIM / 32; ++ks) {
    const int ko = ks * 32 + q * 8;
    const v8s a0 = *(const v8s*)(H + off0 + ko);
    #pragma unroll
    for (int nt = 0; nt < NT; ++nt) {
      const v8s b = *(const v8s*)&buf[((ks * 4 + q) * DOUT + nt * 16 + lm) * 8];
      acc[nt] = __builtin_amdgcn_mfma_f32_16x16x32_bf16(a0, b, acc[nt], 0, 0, 0);
    }
  }
  __syncthreads();   // buf free for epilogue

  // ---- epilogue: stage C into buf (C-layout), then coalesced out
  const int base = blockIdx.x * 128;
  if constexpr (BF16_OUT) {
    #pragma unroll
    for (int nt = 0; nt < NT; ++nt) {
      const int col = nt * 16 + lm;
      const float bv = bias[col];
      #pragma unroll
      for (int r = 0; r < 4; ++r) {
        float v = acc[nt][r] + bv;
        if (RELU) v = v > 0.f ? v : 0.f;
        buf[(lrow0 + q * 4 + r) * DOUT + col] = f2b(v);
      }
    }
    __syncthreads();
    #pragma unroll
    for (int i = tid * 8; i < 128 * DOUT; i += 4096) {
      const int rw = i / DOUT;
      if (base + rw < N_NODES)
        *(uint4*)&Obf[(size_t)(base + rw) * DOUT + (i % DOUT)] = *(const uint4*)&buf[i];
    }
  } else {
    float* fb = (float*)buf;    // 8192 floats = 32 KB (DOUT=64)
    #pragma unroll
    for (int nt = 0; nt < NT; ++nt) {
      const int col = nt * 16 + lm;
      const float bv = bias[col];
      #pragma unroll
      for (int r = 0; r < 4; ++r) {
        float v = acc[nt][r] + bv;
        if (RELU) v = v > 0.f ? v : 0.f;
        fb[(lrow0 + q * 4 + r) * DOUT + col] = v;
      }
    }
    __syncthreads();
    #pragma unroll
    for (int i = tid * 4; i < 128 * DOUT; i += 2048) {
      const int rw = i / DOUT;
      if (base + rw < N_NODES)
        *(float4*)&Ofp[(size_t)(base + rw) * DOUT + (i % DOUT)] = *(const float4*)&fb[i];
    }
  }
}

// ------------------------------------------------- ngnn0: sage0+fc+fc2 fused
// Y = relu( relu( relu(X@Ws0 + agg(X)@Wn0 + b0) @ Wf1 + b1 ) @ Wf2 + b2 )
// Zero barriers, weights from L2-hot global, gather16 (round-11 proven).
// ROUND-13 (this round): 32-ROW BLOCKS (128 threads = 2 waves). Round-11
// showed occupancy 57% with 8 blocks/CU legal -- limiter is grid/tail
// granularity, not residency. aggb 8.7KB -> 16 blocks/CU legal (139KB),
// grid 3125 = 12.2/CU, tail quantum halved. Per-wave code unchanged.
// Round-12 lesson (3rd time): never trade occupancy for traffic.

__global__ __launch_bounds__(128, 8) void ngnn0_kernel(
    const ushort_t* __restrict__ X,
    const ushort_t* __restrict__ Ws0, const ushort_t* __restrict__ Wn0,
    const ushort_t* __restrict__ Wf1, const ushort_t* __restrict__ Wf2,
    const float* __restrict__ b0, const float* __restrict__ bf1,
    const float* __restrict__ bf2,
    const int* __restrict__ row_ptr, const int* __restrict__ ssrc,
    const float* __restrict__ inv_deg,
    ushort_t* __restrict__ O) {
  constexpr int NT = 8;
  constexpr int HP = 136;   // 272B row stride = 17*16B: b128-aligned, 2-way banks
  __shared__ __align__(16) ushort_t aggb[32 * HP];   // 8.7 KB

  const int tid   = threadIdx.x;
  const int wv    = tid >> 6;               // 0..1
  const int lane  = tid & 63;
  const int lm    = lane & 15;
  const int q     = lane >> 4;
  const int lrow0 = wv * 16;
  const int row0  = blockIdx.x * 32 + lrow0;

  // ---- gather: aggb[own 16 rows] = mean of neighbor X rows (wave-local)
  gather16<HP>(X, aggb, row_ptr, ssrc, inv_deg, row0, lrow0, lm, q);

  v4f acc[NT];
  #pragma unroll
  for (int n = 0; n < NT; ++n) acc[n] = (v4f){0.f, 0.f, 0.f, 0.f};

  // ---- phase A: aggb @ Wn0
  for (int ks = 0; ks < K_DIM / 32; ++ks) {
    const int ko = ks * 32 + q * 8;
    const v8s a0 = *(const v8s*)&aggb[(lrow0 + lm) * HP + ko];
    #pragma unroll
    for (int nt = 0; nt < NT; ++nt) {
      const v8s b = *(const v8s*)&Wn0[((ks * 4 + q) * 128 + nt * 16 + lm) * 8];
      acc[nt] = __builtin_amdgcn_mfma_f32_16x16x32_bf16(a0, b, acc[nt], 0, 0, 0);
    }
  }

  // ---- phase B: acc += X[own rows] @ Ws0
  int ra = row0 + lm;  ra = ra < N_NODES ? ra : N_NODES - 1;
  const size_t off0 = (size_t)ra * K_DIM;
  for (int ks = 0; ks < K_DIM / 32; ++ks) {
    const int ko = ks * 32 + q * 8;
    const v8s a0 = *(const v8s*)(X + off0 + ko);
    #pragma unroll
    for (int nt = 0; nt < NT; ++nt) {
      const v8s b = *(const v8s*)&Ws0[((ks * 4 + q) * 128 + nt * 16 + lm) * 8];
      acc[nt] = __builtin_amdgcn_mfma_f32_16x16x32_bf16(a0, b, acc[nt], 0, 0, 0);
    }
  }

  // ---- h0 = relu(acc + b0) -> aggb own rows (C-layout; after phase-A reads
  // in program order -- per-wave DS FIFO keeps read-before-write)
  #pragma unroll
  for (int nt = 0; nt < NT; ++nt) {
    const int col = nt * 16 + lm;
    const float bv = b0[col];
    #pragma unroll
    for (int r = 0; r < 4; ++r) {
      float v = acc[nt][r] + bv;
      v = v > 0.f ? v : 0.f;
      aggb[(lrow0 + q * 4 + r) * HP + col] = f2b(v);
      acc[nt][r] = 0.f;
    }
  }

  // ---- phase C: aggb(h0) @ Wf1
  for (int ks = 0; ks < K_DIM / 32; ++ks) {
    const int ko = ks * 32 + q * 8;
    const v8s a0 = *(const v8s*)&aggb[(lrow0 + lm) * HP + ko];
    #pragma unroll
    for (int nt = 0; nt < NT; ++nt) {
      const v8s b = *(const v8s*)&Wf1[((ks * 4 + q) * 128 + nt * 16 + lm) * 8];
      acc[nt] = __builtin_amdgcn_mfma_f32_16x16x32_bf16(a0, b, acc[nt], 0, 0, 0);
    }
  }

  // ---- h1 = relu(acc + bf1) -> aggb own rows
  #pragma unroll
  for (int nt = 0; nt < NT; ++nt) {
    const int col = nt * 16 + lm;
    const float bv = bf1[col];
    #pragma unroll
    for (int r = 0; r < 4; ++r) {
      float v = acc[nt][r] + bv;
      v = v > 0.f ? v : 0.f;
      aggb[(lrow0 + q * 4 + r) * HP + col] = f2b(v);
      acc[nt][r] = 0.f;
    }
  }

  // ---- phase D: aggb(h1) @ Wf2
  for (int ks = 0; ks < K_DIM / 32; ++ks) {
    const int ko = ks * 32 + q * 8;
    const v8s a0 = *(const v8s*)&aggb[(lrow0 + lm) * HP + ko];
    #pragma unroll
    for (int nt = 0; nt < NT; ++nt) {
      const v8s b = *(const v8s*)&Wf2[((ks * 4 + q) * 128 + nt * 16 + lm) * 8];
      acc[nt] = __builtin_amdgcn_mfma_f32_16x16x32_bf16(a0, b, acc[nt], 0, 0, 0);
    }
  }

  // ---- out = relu(acc + bf2): stage into aggb, then per-wave coalesced
  // write of the wave's own 16 rows (no barrier -- all same-wave data)
  #pragma unroll
  for (int nt = 0; nt < NT; ++nt) {
    const int col = nt * 16 + lm;
    const float bv = bf2[col];
    #pragma unroll
    for (int r = 0; r < 4; ++r) {
      float v = acc[nt][r] + bv;
      v = v > 0.f ? v : 0.f;
      aggb[(lrow0 + q * 4 + r) * HP + col] = f2b(v);
    }
  }
  #pragma unroll
  for (int j = 0; j < 4; ++j) {
    const int idx = j * 64 + lane;    // 0..255: 16 rows x 16 segments
    const int rw  = idx >> 4;
    const int sg  = idx & 15;
    const int grow = row0 + rw;
    if (grow < N_NODES)
      *(uint4*)&O[(size_t)grow * 128 + sg * 8] =
          *(const uint4*)&aggb[(lrow0 + rw) * HP + sg * 8];
  }
}

// ---------------------------------------------------------------- launcher

extern "C" void kernel_launch(void* const* d_in, const int* in_sizes, int n_in,
                              void* d_out, int out_size, void* d_ws, size_t ws_size,
                              hipStream_t stream) {
  const float* x        = (const float*)d_in[0];
  const int*   src      = (const int*)d_in[1];
  const int*   dst      = (const int*)d_in[2];
  const float* w_self0  = (const float*)d_in[3];
  const float* b_self0  = (const float*)d_in[4];
  const float* w_neigh0 = (const float*)d_in[5];
  const float* fc_w     = (const float*)d_in[6];
  const float* fc_b     = (const float*)d_in[7];
  const float* fc2_w    = (const float*)d_in[8];
  const float* fc2_b    = (const float*)d_in[9];
  const float* w_self1  = (const float*)d_in[10];
  const float* b_self1  = (const float*)d_in[11];
  const float* w_neigh1 = (const float*)d_in[12];
  const float* w_self2  = (const float*)d_in[13];
  const float* b_self2  = (const float*)d_in[14];
  const float* w_neigh2 = (const float*)d_in[15];

  char* p = (char*)d_ws;
  auto carve = [&](size_t bytes) {
    void* q = (void*)p;
    p += (bytes + 511) & ~(size_t)511;
    return q;
  };
  const size_t VPLANE = (size_t)VROWS * K_DIM * sizeof(ushort_t);   // 25.6 MB
  ushort_t* X    = (ushort_t*)carve(VPLANE);
  ushort_t* Y    = (ushort_t*)carve(VPLANE);
  ushort_t* Z    = (ushort_t*)carve(VPLANE);
  ushort_t* AGGs = (ushort_t*)carve(VPLANE);
  ushort_t* ws0 = (ushort_t*)carve(K_DIM * 128 * 2);
  ushort_t* wn0 = (ushort_t*)carve(K_DIM * 128 * 2);
  ushort_t* wfc = (ushort_t*)carve(K_DIM * 128 * 2);
  ushort_t* wf2 = (ushort_t*)carve(K_DIM * 128 * 2);
  ushort_t* ws1 = (ushort_t*)carve(K_DIM * 128 * 2);
  ushort_t* wn1 = (ushort_t*)carve(K_DIM * 128 * 2);
  ushort_t* ws2 = (ushort_t*)carve(K_DIM * 64 * 2);
  ushort_t* wn2 = (ushort_t*)carve(K_DIM * 64 * 2);
  int*   ssrc    = (int*)carve((size_t)N_EDGES * 4);
  int*   row_ptr = (int*)carve((size_t)(N_NODES + 1) * 4);
  int*   cursor  = (int*)carve((size_t)N_NODES * 4);
  int*   deg     = (int*)carve((size_t)N_NODES * 4);
  int*   excl    = (int*)carve((size_t)N_NODES * 4);
  int*   parts   = (int*)carve(512 * 4);
  float* inv_deg = (float*)carve((size_t)N_NODES * 4);

  // ---- CSR build (by dst), with cast/swizzle fused into its idle slots
  hipMemsetAsync(deg, 0, (size_t)N_NODES * 4, stream);
  deg_cast_kernel<<<EBLK + CASTB, 256, 0, stream>>>(dst, deg, x, X);
  scan1_swz_kernel<<<NPART + 512, 256, 0, stream>>>(
      deg, excl, parts,
      w_self0, w_neigh0, fc_w, fc2_w, w_self1, w_neigh1, w_self2, w_neigh2,
      ws0, wn0, wfc, wf2, ws1, wn1, ws2, wn2);
  scan3_kernel<<<((N_NODES + 1) + 255) / 256, 256, 0, stream>>>(excl, parts, deg,
                                                                row_ptr, cursor, inv_deg);
  fill_kernel<<<EBLK, 256, 0, stream>>>(src, dst, cursor, ssrc);

  // ---- network: 3 dispatches.
  // ngnn0 (sage0+fc+fc2): X -> Y  (32-row blocks, gather16)
  ngnn0_kernel<<<NBLK, 128, 0, stream>>>(
      X, ws0, wn0, wfc, wf2, b_self0, fc_b, fc2_b,
      row_ptr, ssrc, inv_deg, Y);
  // layer 1: relu(Y@Ws1 + agg(Y)@Wn1 + b) -> Z
  sage_layer_kernel<128, true, true><<<GBLK, 512, 0, stream>>>(
      Y, AGGs, ws1, wn1, b_self1, row_ptr, ssrc, inv_deg, Z, nullptr);
  // layer 2: Z@Ws2 + agg(Z)@Wn2 + b -> d_out (fp32, DOUT=64)
  sage_layer_kernel<64, false, false><<<GBLK, 512, 0, stream>>>(
      Z, AGGs, ws2, wn2, b_self2, row_ptr, ssrc, inv_deg, nullptr, (float*)d_out);
}